// Round 4
// baseline (203.905 us; speedup 1.0000x reference)
//
#include <hip/hip_runtime.h>
#include <hip/hip_fp16.h>

// GCN: N=100000 nodes (4 feats), E=3.2M edges, G=1024 graphs.
// out = mean-pool(tanh(gcn2(tanh(gcn1(embed(x)))))) @ W3.T + b3
//
// gcn_conv rewritten: u[i] = (h[i] @ W^T) * dinv[i];
// out[c] = dinv[c] * (sum_{edges r->c} u[r] + u[c]) + b   (self-loop folded in)
//
// R17: sort machinery attack. (a) LDS bin counters replicated x4 by lane
// group (lane>>4) in BOTH rank passes -- same atomic count, ~4x less
// same-bin serialization; per-bin prefix over replicas merged at scan.
// (b) k_place copy-out: bucket id stored in stageB[] at stage time ->
// direct address, no 9-iter LDS binary search. (c) memset shrunk to
// bucketCnt+doneCnt; pooled/cnt zeroed inside k_agg1. (d) k_out fused
// into k_agg2_pool via done-counter last-block pattern (one launch less).
// R16: 4 adjacent lanes/node in aggs, shfl_xor(1,2) combine.
// R15b: u1 messages fp8 e4m3 (x64, HW cvt_pk) -> ONE uint4 gather/edge.
// Measured walls: LDS-atomic rank pass ~21us x2 (R3/R7); harness 0xAA
// re-poison ~44us fixed; aggs ~10us each (txn-bound, R16 post-mortem).

constexpr int BLK  = 256;
constexpr int NPB  = 256;            // dst nodes per bucket (dloc = 8 bits)
constexpr int NBMX = 512;            // padded bin count (NB = 391)
constexpr int CAPB = 9216;           // slots/bucket; mean 8184, sigma ~90
constexpr int PBLK = 512;            // k_place block size
constexpr int CAPS = 6144;           // k_place chunk = PBLK * EPT
constexpr int EPT  = 12;             // edges/thread in k_place
constexpr int SBLK = 512;            // k_sort block size
constexpr int NIT4 = 5;              // uint4 iters: ceil(CAPB/(SBLK*4))
constexpr float S8 = 64.0f;          // fp8 scale for u1 messages

// Single-pass placement, ONE LDS-atomic pass (x4 replicated bins):
// o = atomicAdd(&pos[r][b],1) is both offset and histogram; (entry, r|b|o)
// in registers; scan merges replicas -> sstart + per-replica bases;
// reserve global space; stage (entry + bucket id); direct-lookup copy-out.
// entry = (dloc<<17) | src.
__global__ void k_place(const int4* __restrict__ row4, const int4* __restrict__ col4,
                        int* __restrict__ bucketCnt, unsigned int* __restrict__ data,
                        int E, int NB) {
    __shared__ unsigned int stage[CAPS];                    // 24.6 KB
    __shared__ unsigned short stageB[CAPS];                 // 12.3 KB
    __shared__ int pos[4][NBMX];                            // 8 KB
    __shared__ int sstart[NBMX], lbase[NBMX];               // 4 KB
    __shared__ int wsum[8];
    int t = threadIdx.x;                        // 0..511
    int lane = t & 63, w = t >> 6;
    int rep = (lane >> 4) & 3;                  // replica by lane group
    int begin = blockIdx.x * CAPS;
    int end = min(E, begin + CAPS);
    int csize = end - begin;                    // multiple of 4
    int q0 = begin >> 2, q1 = end >> 2;
#pragma unroll
    for (int rr = 0; rr < 4; rr++) pos[rr][t] = 0;
    __syncthreads();
    unsigned int ent[EPT];
    int meta[EPT];
#pragma unroll
    for (int it = 0; it < EPT / 4; it++) {
        int i = q0 + t + it * PBLK;
        bool ok = i < q1;
        int4 c = ok ? col4[i] : make_int4(0, 0, 0, 0);
        int4 r = ok ? row4[i] : make_int4(0, 0, 0, 0);
#pragma unroll
        for (int k = 0; k < 4; k++) {
            int cc = ((const int*)&c)[k];
            int rr = ((const int*)&r)[k];
            int b = cc >> 8;
            int o = ok ? atomicAdd(&pos[rep][b], 1) : 0;
            ent[it * 4 + k] = ((unsigned int)(cc & 255) << 17) | (unsigned int)rr;
            // meta = (rep<<22) | (b<<13) | o   (b<512: 9b, o<6144: 13b)
            meta[it * 4 + k] = ok ? ((rep << 22) | (b << 13) | o) : -1;
        }
    }
    __syncthreads();
    // scan 512 bins, thread owns bin t; merge 4 replicas
    int p0 = pos[0][t], p1 = pos[1][t], p2 = pos[2][t], p3 = pos[3][t];
    int v = p0 + p1 + p2 + p3;
    int sc = v;
#pragma unroll
    for (int off = 1; off < 64; off <<= 1) {
        int o = __shfl_up(sc, off, 64);
        if (lane >= off) sc += o;
    }
    if (lane == 63) wsum[w] = sc;
    __syncthreads();
    int pre = 0;
#pragma unroll
    for (int i = 0; i < 8; i++) if (i < w) pre += wsum[i];
    int excl = sc + pre - v;
    sstart[t] = excl;
    lbase[t] = v ? atomicAdd(&bucketCnt[t], v) : 0;
    // per-replica base offsets within bin t (overwrite counters)
    pos[0][t] = 0;
    pos[1][t] = p0;
    pos[2][t] = p0 + p1;
    pos[3][t] = p0 + p1 + p2;
    __syncthreads();
#pragma unroll
    for (int k = 0; k < EPT; k++) {
        int m = meta[k];
        if (m >= 0) {
            int rr = m >> 22;
            int b  = (m >> 13) & 0x1FF;
            int o  = m & 0x1FFF;
            int idx = sstart[b] + pos[rr][b] + o;
            stage[idx]  = ent[k];
            stageB[idx] = (unsigned short)b;
        }
    }
    __syncthreads();
    for (int k = t; k < csize; k += PBLK) {
        int b = stageB[k];
        data[(unsigned int)b * CAPB + (unsigned int)(lbase[b] + (k - sstart[b]))] = stage[k];
    }
}

// Per-bucket one-pass counting sort (edges in registers via uint4 loads,
// x4 replicated bins, scatter straight to the L2-resident bucket region)
// + dinv + rs/re + fused node1 (u1 encoded fp8 e4m3 x64). BLK=512.
__global__ void k_sort_node1(unsigned int* __restrict__ data,
                             const int* __restrict__ bucketCnt,
                             const float4* __restrict__ x,
                             const float* __restrict__ Wemb, const float* __restrict__ bemb,
                             const float* __restrict__ W1,
                             int* __restrict__ rs, int* __restrict__ re,
                             float* __restrict__ dinv, uint4* __restrict__ u1q, int n) {
    __shared__ int pos[4][NPB], startl[NPB];
    __shared__ int wsum[4];
    int b = blockIdx.x;
    int t = threadIdx.x;                        // 0..511
    int lane = t & 63;
    int rep = (lane >> 4) & 3;
    int base = b * CAPB;
    int cnt = min(bucketCnt[b], CAPB);
    ((int*)pos)[t] = 0;
    ((int*)pos)[t + SBLK] = 0;                  // 4*256 = 1024 ints
    __syncthreads();
    const uint4* data4 = (const uint4*)(data + base);   // base = b*9216, 16B aligned
    unsigned int ent[NIT4 * 4];                 // src (17 bits)
    int off[NIT4 * 4];                          // (rep<<22)|(dloc<<14)|o ; o < CAPB < 16384
#pragma unroll
    for (int it = 0; it < NIT4; it++) {
        int i4 = t + it * SBLK;                 // quad index
        int i = i4 * 4;
        uint4 p4 = (i < cnt) ? data4[i4] : make_uint4(0, 0, 0, 0);
#pragma unroll
        for (int k = 0; k < 4; k++) {
            int idx = it * 4 + k;
            if (i + k < cnt) {
                unsigned int p = ((const unsigned int*)&p4)[k];
                int dloc = (int)(p >> 17);
                int o = atomicAdd(&pos[rep][dloc], 1);
                ent[idx] = p & 0x1FFFF;
                off[idx] = (rep << 22) | (dloc << 14) | o;
            } else off[idx] = -1;
        }
    }
    __syncthreads();
    int node = b * NPB + t;
    float d = 0.0f;
    if (t < NPB) {
        int w = t >> 6;
        int p0 = pos[0][t], p1 = pos[1][t], p2 = pos[2][t], p3 = pos[3][t];
        int v = p0 + p1 + p2 + p3;
        int sc = v;
#pragma unroll
        for (int o = 1; o < 64; o <<= 1) {
            int s = __shfl_up(sc, o, 64);
            if (lane >= o) sc += s;
        }
        if (lane == 63) wsum[w] = sc;
        __syncthreads();
        int pre = 0;
#pragma unroll
        for (int i = 0; i < 4; i++) if (i < w) pre += wsum[i];
        int excl = sc + pre - v;
        startl[t] = excl;
        pos[0][t] = 0;
        pos[1][t] = p0;
        pos[2][t] = p0 + p1;
        pos[3][t] = p0 + p1 + p2;
        if (node < n) {
            rs[node] = base + excl;
            re[node] = base + excl + v;
            d = rsqrtf((float)v + 1.0f);        // +1 self-loop
            dinv[node] = d;
        }
    } else {
        __syncthreads();
    }
    __syncthreads();
#pragma unroll
    for (int it = 0; it < NIT4 * 4; it++) {
        int m = off[it];
        if (m >= 0) {
            int rr = (m >> 22) & 3;
            int dl = (m >> 14) & 255;
            int o  = m & 0x3FFF;
            data[base + startl[dl] + pos[rr][dl] + o] = ent[it];
        }
    }
    if (t < NPB && node < n) {
        float4 xi = x[node];
        float h0[7];
#pragma unroll
        for (int j = 0; j < 4; j++) h0[j] = xi.x * Wemb[j] + bemb[j];
        h0[4] = xi.y; h0[5] = xi.z; h0[6] = xi.w;
        float s[16];
#pragma unroll
        for (int f = 0; f < 16; f++) {
            float tt = 0.0f;
#pragma unroll
            for (int j = 0; j < 7; j++) tt += h0[j] * W1[f * 7 + j];
            s[f] = tt * d * S8;                 // fp8 scale folded here
        }
        unsigned int w0, w1, w2, w3;
        w0 = __builtin_amdgcn_cvt_pk_fp8_f32(s[0],  s[1],  0,  false);
        w0 = __builtin_amdgcn_cvt_pk_fp8_f32(s[2],  s[3],  w0, true);
        w1 = __builtin_amdgcn_cvt_pk_fp8_f32(s[4],  s[5],  0,  false);
        w1 = __builtin_amdgcn_cvt_pk_fp8_f32(s[6],  s[7],  w1, true);
        w2 = __builtin_amdgcn_cvt_pk_fp8_f32(s[8],  s[9],  0,  false);
        w2 = __builtin_amdgcn_cvt_pk_fp8_f32(s[10], s[11], w2, true);
        w3 = __builtin_amdgcn_cvt_pk_fp8_f32(s[12], s[13], 0,  false);
        w3 = __builtin_amdgcn_cvt_pk_fp8_f32(s[14], s[15], w3, true);
        u1q[node] = make_uint4(w0, w1, w2, w3);
    }
}

typedef float vfloat2 __attribute__((vector_size(8)));   // cvt_pk_f32_fp8 return type

// fp8 e4m3 uint4 (16 msgs) decode-accumulate into f32[16]
__device__ __forceinline__ void dec16_add(uint4 q, float* acc) {
#pragma unroll
    for (int w = 0; w < 4; w++) {
        unsigned int u = ((const unsigned int*)&q)[w];
        vfloat2 lo = __builtin_amdgcn_cvt_pk_f32_fp8(u, false);
        vfloat2 hi = __builtin_amdgcn_cvt_pk_f32_fp8(u, true);
        acc[4 * w + 0] += lo[0]; acc[4 * w + 1] += lo[1];
        acc[4 * w + 2] += hi[0]; acc[4 * w + 3] += hi[1];
    }
}

// Layer 1: 4 adjacent lanes/node, lane j takes edges s+j, s+j+4, ...
// ONE uint4 (16 fp8) gather per edge; partials combined via shfl_xor(1,2).
// Also zeroes pooled/cnt (first 36 blocks) for the fused pool downstream.
// Epilogue (all 4 lanes compute, j==0 stores): h1 = tanh(dinv/S8*acc+b1);
// u2h = fp16((h1 @ W2^T) * dinv), one uint4 store.
__global__ void k_agg1(const unsigned int* __restrict__ sorted,
                       const int* __restrict__ rs, const int* __restrict__ re,
                       const uint4* __restrict__ u1q, const float* __restrict__ dinv,
                       const float* __restrict__ b1, const float* __restrict__ W2,
                       uint4* __restrict__ u2q, float* __restrict__ pooledz,
                       int n, int G) {
    int tt = blockIdx.x * BLK + threadIdx.x;
    if (tt < 9 * G) pooledz[tt] = 0.0f;         // pooled[8G] + cnt[G] contiguous
    int node = tt >> 2;
    int j = tt & 3;
    if (node >= n) return;
    int s = rs[node], e = re[node];
    float acc[16];
#pragma unroll
    for (int k = 0; k < 16; k++) acc[k] = 0.0f;
    int i = s + j;
    for (; i + 4 < e; i += 8) {                 // 2 gathers in flight
        uint4 q0 = u1q[sorted[i]];
        uint4 q1 = u1q[sorted[i + 4]];
        dec16_add(q0, acc);
        dec16_add(q1, acc);
    }
    if (i < e) {
        uint4 q = u1q[sorted[i]];
        dec16_add(q, acc);
    }
    if (j == 0) {                               // self-loop term, added once
        uint4 qs = u1q[node];
        dec16_add(qs, acc);
    }
#pragma unroll
    for (int k = 0; k < 16; k++) {
        acc[k] += __shfl_xor(acc[k], 1, 64);
        acc[k] += __shfl_xor(acc[k], 2, 64);
    }
    float d = dinv[node];
    float dS = d * (1.0f / S8);                 // undo fp8 scale
    float h1[16];
#pragma unroll
    for (int k = 0; k < 16; k++) h1[k] = tanhf(dS * acc[k] + b1[k]);
    float r[8];
#pragma unroll
    for (int g = 0; g < 8; g++) {
        float ttv = 0.0f;
#pragma unroll
        for (int k = 0; k < 16; k++) ttv += h1[k] * W2[g * 16 + k];
        r[g] = ttv * d;
    }
    if (j == 0) {
        union { __half2 h2[4]; uint4 u4; } pk;
#pragma unroll
        for (int q = 0; q < 4; q++) pk.h2[q] = __floats2half2_rn(r[2 * q], r[2 * q + 1]);
        u2q[node] = pk.u4;
    }
}

// Layer 2 + POOL + OUT fused: 4 adjacent lanes/node, uint4 gathers;
// partials via shfl_xor(1,2); stride-4 wave-segmented pool reduction;
// segment heads atomicAdd into pooled/cnt; LAST block (done-counter)
// computes the 1024-graph head output.
__global__ void k_agg2_pool(const unsigned int* __restrict__ sorted,
                            const int* __restrict__ rs, const int* __restrict__ re,
                            const uint4* __restrict__ u2q, const float* __restrict__ dinv,
                            const float* __restrict__ b2, const int* __restrict__ batch,
                            float* __restrict__ pooled, float* __restrict__ cnt,
                            const float* __restrict__ W3, const float* __restrict__ b3,
                            float* __restrict__ out, unsigned int* __restrict__ doneCnt,
                            int n, int G) {
    int tt = blockIdx.x * BLK + threadIdx.x;
    int node = tt >> 2;
    int j = tt & 3;
    int lane = threadIdx.x & 63;
    bool valid = node < n;
    float h[8];
#pragma unroll
    for (int k = 0; k < 8; k++) h[k] = 0.0f;
    int g = -1;
    float c = 0.0f;
    if (valid) {
        int s = rs[node], e = re[node];
        float acc[8];
#pragma unroll
        for (int k = 0; k < 8; k++) acc[k] = 0.0f;
        int i = s + j;
        for (; i + 4 < e; i += 8) {
            uint4 q0 = u2q[sorted[i]];
            uint4 q1 = u2q[sorted[i + 4]];
            const __half2* p0 = (const __half2*)&q0;
            const __half2* p1 = (const __half2*)&q1;
#pragma unroll
            for (int k = 0; k < 4; k++) {
                float2 a0 = __half22float2(p0[k]);
                float2 a1 = __half22float2(p1[k]);
                acc[2*k]   += a0.x + a1.x;
                acc[2*k+1] += a0.y + a1.y;
            }
        }
        if (i < e) {
            uint4 q = u2q[sorted[i]];
            const __half2* p = (const __half2*)&q;
#pragma unroll
            for (int k = 0; k < 4; k++) {
                float2 a = __half22float2(p[k]);
                acc[2*k]   += a.x;
                acc[2*k+1] += a.y;
            }
        }
        if (j == 0) {                           // self-loop, added once
            uint4 qs = u2q[node];
            const __half2* ps = (const __half2*)&qs;
#pragma unroll
            for (int k = 0; k < 4; k++) {
                float2 a = __half22float2(ps[k]);
                acc[2*k]   += a.x;
                acc[2*k+1] += a.y;
            }
        }
#pragma unroll
        for (int k = 0; k < 8; k++) {
            acc[k] += __shfl_xor(acc[k], 1, 64);
            acc[k] += __shfl_xor(acc[k], 2, 64);
        }
        if (j == 0) {
            float d = dinv[node];
#pragma unroll
            for (int k = 0; k < 8; k++) h[k] = tanhf(d * acc[k] + b2[k]);
            g = batch[node];
            c = 1.0f;
        }
    }
    // stride-4 segmented reduction: base lanes (j==0) hold 16 consecutive
    // nodes per wave; offsets 4..32 only ever read base lanes.
#pragma unroll
    for (int off = 4; off < 64; off <<= 1) {
        int gn = __shfl_down(g, off, 64);
        float cn = __shfl_down(c, off, 64);
        float hn[8];
#pragma unroll
        for (int k = 0; k < 8; k++) hn[k] = __shfl_down(h[k], off, 64);
        bool take = (lane + off < 64) && (gn == g);
        if (take) {
            c += cn;
#pragma unroll
            for (int k = 0; k < 8; k++) h[k] += hn[k];
        }
    }
    int gprev = __shfl_up(g, 4, 64);
    bool head = valid && (j == 0) && (lane == 0 || gprev != g);
    if (head) {
#pragma unroll
        for (int k = 0; k < 8; k++) atomicAdd(&pooled[g * 8 + k], h[k]);
        atomicAdd(&cnt[g], c);
    }
    // last-block computes the head output (saves the k_out launch)
    __shared__ int islast;
    __syncthreads();                            // drain this block's atomics
    if (threadIdx.x == 0) {
        __threadfence();
        unsigned int v = atomicAdd(doneCnt, 1u);
        islast = (v == gridDim.x - 1) ? 1 : 0;
    }
    __syncthreads();
    if (islast) {
        __threadfence();                        // acquire all blocks' pool writes
        for (int gg = (int)threadIdx.x; gg < G; gg += BLK) {
            float cc = fmaxf(cnt[gg], 1.0f);
            float tsum = 0.0f;
#pragma unroll
            for (int k = 0; k < 8; k++) tsum += pooled[gg * 8 + k] * W3[k];
            out[gg] = tsum / cc + b3[0];
        }
    }
}

extern "C" void kernel_launch(void* const* d_in, const int* in_sizes, int n_in,
                              void* d_out, int out_size, void* d_ws, size_t ws_size,
                              hipStream_t stream) {
    const float* x    = (const float*)d_in[0];
    const int*   ei   = (const int*)d_in[1];
    const int*   batch= (const int*)d_in[2];
    const float* Wemb = (const float*)d_in[3];
    const float* bemb = (const float*)d_in[4];
    const float* W1   = (const float*)d_in[5];
    const float* b1   = (const float*)d_in[6];
    const float* W2   = (const float*)d_in[7];
    const float* b2   = (const float*)d_in[8];
    const float* W3   = (const float*)d_in[9];
    const float* b3   = (const float*)d_in[10];
    float* out = (float*)d_out;

    const int n = in_sizes[2];        // 100000
    const int E = in_sizes[1] / 2;    // 3200000
    const int G = out_size;           // 1024
    const int* row = ei;
    const int* col = ei + E;
    const int NB = (n + NPB - 1) / NPB;   // 391

    // workspace (4B words): dinv[n] | u1q(8n reserved, 4n used: fp8 16B/node) |
    //   u2h(4n) | rs[n] | re[n] | bucketCnt[NBMX] | doneCnt+pad[64] |
    //   pooled[8G] | cnt[G] | data[NB*CAPB]  (~20.5 MB)
    float* ws    = (float*)d_ws;
    float* dinv  = ws;                       // n
    uint4* u1q   = (uint4*)(ws + n);         // 4n words used (16 fp8/node)
    __half* u2h  = (__half*)(ws + 9 * n);    // 4n words (8 halves/node)
    int* rs      = (int*)(ws + 13 * n);      // n
    int* re      = rs + n;                   // n
    int* bucketCnt = re + n;                 // NBMX
    unsigned int* doneCnt = (unsigned int*)(bucketCnt + NBMX);  // 1 (+63 pad)
    float* pooled  = (float*)(bucketCnt + NBMX + 64);           // 8G
    float* cnt     = pooled + 8 * G;                            // G
    unsigned int* data = (unsigned int*)(cnt + G);              // NB*CAPB

    int gridP = (E + CAPS - 1) / CAPS;       // 521 blocks, chunk = 6144
    int gridA = (4 * n + BLK - 1) / BLK;     // 1563 blocks, 4 lanes/node

    // small memset: bucketCnt + doneCnt only (pooled/cnt zeroed in k_agg1)
    hipMemsetAsync(bucketCnt, 0, (NBMX + 64) * sizeof(int), stream);
    k_place<<<gridP, PBLK, 0, stream>>>((const int4*)row, (const int4*)col,
                                        bucketCnt, data, E, NB);
    k_sort_node1<<<NB, SBLK, 0, stream>>>(data, bucketCnt, (const float4*)x,
                                          Wemb, bemb, W1, rs, re, dinv, u1q, n);
    k_agg1<<<gridA, BLK, 0, stream>>>(data, rs, re, u1q,
                                      dinv, b1, W2, (uint4*)u2h, pooled, n, G);
    k_agg2_pool<<<gridA, BLK, 0, stream>>>(data, rs, re,
                                           (const uint4*)u2h, dinv, b2,
                                           batch, pooled, cnt, W3, b3, out,
                                           doneCnt, n, G);
}

// Round 5
// 196.080 us; speedup vs baseline: 1.0399x; 1.0399x over previous
//
#include <hip/hip_runtime.h>
#include <hip/hip_fp16.h>

// GCN: N=100000 nodes (4 feats), E=3.2M edges, G=1024 graphs.
// out = mean-pool(tanh(gcn2(tanh(gcn1(embed(x)))))) @ W3.T + b3
//
// gcn_conv rewritten: u[i] = (h[i] @ W^T) * dinv[i];
// out[c] = dinv[c] * (sum_{edges r->c} u[r] + u[c]) + b   (self-loop folded in)
//
// R18: R17 reverted (its fused-k_out __threadfence was ~+10us on k_agg2_pool;
// rank-replication unattributed). Aggs restructured: 8 lanes/node, 4-slot
// batched prefetch -- 4 independent sorted loads then 4 independent gathers
// per 32-edge round (mean degree = one round), so the dependent-latency
// chain is ~1 round instead of ~4, and waves double to 12.5K. Combine via
// shfl_xor(1,2,4); agg2 pool promoted to stride-8 segmented reduction.
// R16: sorted[] 8-lane coalesced reads. R15b: u1 fp8 e4m3 (x64, cvt_pk),
// ONE uint4 gather/edge. Measured walls: rank pass ~21us x2; harness 0xAA
// re-poison ~44us fixed; R4 profile: k_agg2_pool was 55us latency-bound.

constexpr int BLK  = 256;
constexpr int NPB  = 256;            // dst nodes per bucket (dloc = 8 bits)
constexpr int NBMX = 512;            // padded bin count (NB = 391)
constexpr int CAPB = 9216;           // slots/bucket; mean 8184, sigma ~90
constexpr int PBLK = 512;            // k_place block size
constexpr int CAPS = 6144;           // k_place chunk = PBLK * EPT
constexpr int EPT  = 12;             // edges/thread in k_place
constexpr int SBLK = 512;            // k_sort block size
constexpr int NIT4 = 5;              // uint4 iters: ceil(CAPB/(SBLK*4))
constexpr float S8 = 64.0f;          // fp8 scale for u1 messages

// Single-pass placement, ONE LDS-atomic pass: o = atomicAdd(&pos[b],1) is
// both offset and histogram; (entry, b|o) in registers; scan pos -> sstart;
// reserve global space; stage; binary-search flat copy-out (runs ~16 entries).
// entry = (dloc<<17) | src.
__global__ void k_place(const int4* __restrict__ row4, const int4* __restrict__ col4,
                        int* __restrict__ bucketCnt, unsigned int* __restrict__ data,
                        int E, int NB) {
    __shared__ unsigned int stage[CAPS];                    // 24.6 KB
    __shared__ int pos[NBMX], sstart[NBMX], lbase[NBMX];    // 6 KB
    __shared__ int wsum[8];
    int t = threadIdx.x;                        // 0..511
    int lane = t & 63, w = t >> 6;
    int begin = blockIdx.x * CAPS;
    int end = min(E, begin + CAPS);
    int csize = end - begin;                    // multiple of 4
    int q0 = begin >> 2, q1 = end >> 2;
    if (t < NBMX) pos[t] = 0;
    __syncthreads();
    unsigned int ent[EPT];
    int meta[EPT];
#pragma unroll
    for (int it = 0; it < EPT / 4; it++) {
        int i = q0 + t + it * PBLK;
        bool ok = i < q1;
        int4 c = ok ? col4[i] : make_int4(0, 0, 0, 0);
        int4 r = ok ? row4[i] : make_int4(0, 0, 0, 0);
#pragma unroll
        for (int k = 0; k < 4; k++) {
            int cc = ((const int*)&c)[k];
            int rr = ((const int*)&r)[k];
            int b = cc >> 8;
            int o = ok ? atomicAdd(&pos[b], 1) : 0;
            ent[it * 4 + k] = ((unsigned int)(cc & 255) << 17) | (unsigned int)rr;
            meta[it * 4 + k] = ok ? ((b << 13) | o) : -1;
        }
    }
    __syncthreads();
    // scan 512 bins, thread owns bin t
    int v = pos[t];
    int sc = v;
#pragma unroll
    for (int off = 1; off < 64; off <<= 1) {
        int o = __shfl_up(sc, off, 64);
        if (lane >= off) sc += o;
    }
    if (lane == 63) wsum[w] = sc;
    __syncthreads();
    int pre = 0;
#pragma unroll
    for (int i = 0; i < 8; i++) if (i < w) pre += wsum[i];
    int excl = sc + pre - v;
    sstart[t] = excl;
    lbase[t] = v ? atomicAdd(&bucketCnt[t], v) : 0;
    __syncthreads();
#pragma unroll
    for (int k = 0; k < EPT; k++) {
        int m = meta[k];
        if (m >= 0) stage[sstart[m >> 13] + (m & 0x1FFF)] = ent[k];
    }
    __syncthreads();
    for (int k = t; k < csize; k += PBLK) {
        int lo = 0, hi = NB - 1;
        while (lo < hi) { int m = (lo + hi + 1) >> 1; if (sstart[m] <= k) lo = m; else hi = m - 1; }
        data[(unsigned int)lo * CAPB + (unsigned int)(lbase[lo] + (k - sstart[lo]))] = stage[k];
    }
}

// Per-bucket one-pass counting sort (edges in registers via uint4 loads,
// scatter straight to the L2-resident bucket region) + dinv + rs/re + fused
// node1 (u1 encoded fp8 e4m3 x64 -> one uint4 per node). BLK=512.
__global__ void k_sort_node1(unsigned int* __restrict__ data,
                             const int* __restrict__ bucketCnt,
                             const float4* __restrict__ x,
                             const float* __restrict__ Wemb, const float* __restrict__ bemb,
                             const float* __restrict__ W1,
                             int* __restrict__ rs, int* __restrict__ re,
                             float* __restrict__ dinv, uint4* __restrict__ u1q, int n) {
    __shared__ int pos[NPB], startl[NPB];
    __shared__ int wsum[4];
    int b = blockIdx.x;
    int t = threadIdx.x;                        // 0..511
    int base = b * CAPB;
    int cnt = min(bucketCnt[b], CAPB);
    if (t < NPB) pos[t] = 0;
    __syncthreads();
    const uint4* data4 = (const uint4*)(data + base);   // base = b*9216, 16B aligned
    unsigned int ent[NIT4 * 4];                 // src (17 bits)
    int off[NIT4 * 4];                          // (dloc<<14)|o ; o < CAPB < 16384
#pragma unroll
    for (int it = 0; it < NIT4; it++) {
        int i4 = t + it * SBLK;                 // quad index
        int i = i4 * 4;
        uint4 p4 = (i < cnt) ? data4[i4] : make_uint4(0, 0, 0, 0);
#pragma unroll
        for (int k = 0; k < 4; k++) {
            int idx = it * 4 + k;
            if (i + k < cnt) {
                unsigned int p = ((const unsigned int*)&p4)[k];
                int dloc = (int)(p >> 17);
                int o = atomicAdd(&pos[dloc], 1);
                ent[idx] = p & 0x1FFFF;
                off[idx] = (dloc << 14) | o;
            } else off[idx] = -1;
        }
    }
    __syncthreads();
    int node = b * NPB + t;
    float d = 0.0f;
    if (t < NPB) {
        int lane = t & 63, w = t >> 6;
        int v = pos[t];
        int sc = v;
#pragma unroll
        for (int o = 1; o < 64; o <<= 1) {
            int s = __shfl_up(sc, o, 64);
            if (lane >= o) sc += s;
        }
        if (lane == 63) wsum[w] = sc;
        __syncthreads();
        int pre = 0;
#pragma unroll
        for (int i = 0; i < 4; i++) if (i < w) pre += wsum[i];
        int excl = sc + pre - v;
        startl[t] = excl;
        if (node < n) {
            rs[node] = base + excl;
            re[node] = base + excl + v;
            d = rsqrtf((float)v + 1.0f);        // +1 self-loop
            dinv[node] = d;
        }
    } else {
        __syncthreads();
    }
    __syncthreads();
#pragma unroll
    for (int it = 0; it < NIT4 * 4; it++) {
        int m = off[it];
        if (m >= 0) data[base + startl[m >> 14] + (m & 0x3FFF)] = ent[it];
    }
    if (t < NPB && node < n) {
        float4 xi = x[node];
        float h0[7];
#pragma unroll
        for (int j = 0; j < 4; j++) h0[j] = xi.x * Wemb[j] + bemb[j];
        h0[4] = xi.y; h0[5] = xi.z; h0[6] = xi.w;
        float s[16];
#pragma unroll
        for (int f = 0; f < 16; f++) {
            float tt = 0.0f;
#pragma unroll
            for (int j = 0; j < 7; j++) tt += h0[j] * W1[f * 7 + j];
            s[f] = tt * d * S8;                 // fp8 scale folded here
        }
        unsigned int w0, w1, w2, w3;
        w0 = __builtin_amdgcn_cvt_pk_fp8_f32(s[0],  s[1],  0,  false);
        w0 = __builtin_amdgcn_cvt_pk_fp8_f32(s[2],  s[3],  w0, true);
        w1 = __builtin_amdgcn_cvt_pk_fp8_f32(s[4],  s[5],  0,  false);
        w1 = __builtin_amdgcn_cvt_pk_fp8_f32(s[6],  s[7],  w1, true);
        w2 = __builtin_amdgcn_cvt_pk_fp8_f32(s[8],  s[9],  0,  false);
        w2 = __builtin_amdgcn_cvt_pk_fp8_f32(s[10], s[11], w2, true);
        w3 = __builtin_amdgcn_cvt_pk_fp8_f32(s[12], s[13], 0,  false);
        w3 = __builtin_amdgcn_cvt_pk_fp8_f32(s[14], s[15], w3, true);
        u1q[node] = make_uint4(w0, w1, w2, w3);
    }
}

typedef float vfloat2 __attribute__((vector_size(8)));   // cvt_pk_f32_fp8 return type

// fp8 e4m3 uint4 (16 msgs) decode-accumulate into f32[16]
__device__ __forceinline__ void dec16_add(uint4 q, float* acc) {
#pragma unroll
    for (int w = 0; w < 4; w++) {
        unsigned int u = ((const unsigned int*)&q)[w];
        vfloat2 lo = __builtin_amdgcn_cvt_pk_f32_fp8(u, false);
        vfloat2 hi = __builtin_amdgcn_cvt_pk_f32_fp8(u, true);
        acc[4 * w + 0] += lo[0]; acc[4 * w + 1] += lo[1];
        acc[4 * w + 2] += hi[0]; acc[4 * w + 3] += hi[1];
    }
}

// Layer 1: 8 lanes/node, lane jj takes edges s+jj, s+jj+8, ... Per 32-edge
// round: 4 independent (clamped) sorted loads, then 4 independent uint4
// gathers, then predicated decode -- one latency exposure per round.
// Partials via shfl_xor(1,2,4). Epilogue on all lanes, jj==0 stores
// u2h = fp16((tanh(dinv/S8*acc+b1) @ W2^T) * dinv).
__global__ void k_agg1(const unsigned int* __restrict__ sorted,
                       const int* __restrict__ rs, const int* __restrict__ re,
                       const uint4* __restrict__ u1q, const float* __restrict__ dinv,
                       const float* __restrict__ b1, const float* __restrict__ W2,
                       uint4* __restrict__ u2q, int n) {
    int tt = blockIdx.x * BLK + threadIdx.x;
    int node = tt >> 3;
    int jj = tt & 7;
    if (node >= n) return;
    int s = rs[node], e = re[node];
    float acc[16];
#pragma unroll
    for (int k = 0; k < 16; k++) acc[k] = 0.0f;
    for (int ib = s; ib < e; ib += 32) {
        int last = e - 1;                       // e > ib >= 0 here
        int i0 = ib + jj;
        int i1 = i0 + 8, i2 = i0 + 16, i3 = i0 + 24;
        int c0 = min(i0, last), c1 = min(i1, last);
        int c2 = min(i2, last), c3 = min(i3, last);
        int x0 = sorted[c0];                    // 4 independent loads
        int x1 = sorted[c1];
        int x2 = sorted[c2];
        int x3 = sorted[c3];
        uint4 q0 = u1q[x0];                     // 4 independent gathers
        uint4 q1 = u1q[x1];
        uint4 q2 = u1q[x2];
        uint4 q3 = u1q[x3];
        if (i0 <= last) dec16_add(q0, acc);     // predicated accumulate
        if (i1 <= last) dec16_add(q1, acc);
        if (i2 <= last) dec16_add(q2, acc);
        if (i3 <= last) dec16_add(q3, acc);
    }
    if (jj == 0) {                              // self-loop term, added once
        uint4 qs = u1q[node];
        dec16_add(qs, acc);
    }
#pragma unroll
    for (int k = 0; k < 16; k++) {
        acc[k] += __shfl_xor(acc[k], 1, 64);
        acc[k] += __shfl_xor(acc[k], 2, 64);
        acc[k] += __shfl_xor(acc[k], 4, 64);
    }
    float d = dinv[node];
    float dS = d * (1.0f / S8);                 // undo fp8 scale
    float h1[16];
#pragma unroll
    for (int k = 0; k < 16; k++) h1[k] = tanhf(dS * acc[k] + b1[k]);
    float r[8];
#pragma unroll
    for (int g = 0; g < 8; g++) {
        float ttv = 0.0f;
#pragma unroll
        for (int k = 0; k < 16; k++) ttv += h1[k] * W2[g * 16 + k];
        r[g] = ttv * d;
    }
    if (jj == 0) {
        union { __half2 h2[4]; uint4 u4; } pk;
#pragma unroll
        for (int q = 0; q < 4; q++) pk.h2[q] = __floats2half2_rn(r[2 * q], r[2 * q + 1]);
        u2q[node] = pk.u4;
    }
}

// Layer 2 + POOL fused: 8 lanes/node (8 nodes/wave), same 4-slot batched
// prefetch; partials via shfl_xor(1,2,4); h2 on base lanes; stride-8
// wave-segmented reduction over sorted batch (offsets 8..32), segment
// heads atomicAdd 8 features + count into pooled/cnt.
__global__ void k_agg2_pool(const unsigned int* __restrict__ sorted,
                            const int* __restrict__ rs, const int* __restrict__ re,
                            const uint4* __restrict__ u2q, const float* __restrict__ dinv,
                            const float* __restrict__ b2, const int* __restrict__ batch,
                            float* __restrict__ pooled, float* __restrict__ cnt, int n) {
    int tt = blockIdx.x * BLK + threadIdx.x;
    int node = tt >> 3;
    int jj = tt & 7;
    int lane = threadIdx.x & 63;
    bool valid = node < n;
    float h[8];
#pragma unroll
    for (int k = 0; k < 8; k++) h[k] = 0.0f;
    int g = -1;
    float c = 0.0f;
    if (valid) {
        int s = rs[node], e = re[node];
        float acc[8];
#pragma unroll
        for (int k = 0; k < 8; k++) acc[k] = 0.0f;
        for (int ib = s; ib < e; ib += 32) {
            int last = e - 1;
            int i0 = ib + jj;
            int i1 = i0 + 8, i2 = i0 + 16, i3 = i0 + 24;
            int c0 = min(i0, last), c1 = min(i1, last);
            int c2 = min(i2, last), c3 = min(i3, last);
            int x0 = sorted[c0];
            int x1 = sorted[c1];
            int x2 = sorted[c2];
            int x3 = sorted[c3];
            uint4 q0 = u2q[x0];
            uint4 q1 = u2q[x1];
            uint4 q2 = u2q[x2];
            uint4 q3 = u2q[x3];
            const __half2* p0 = (const __half2*)&q0;
            const __half2* p1 = (const __half2*)&q1;
            const __half2* p2 = (const __half2*)&q2;
            const __half2* p3 = (const __half2*)&q3;
            if (i0 <= last) {
#pragma unroll
                for (int k = 0; k < 4; k++) {
                    float2 a = __half22float2(p0[k]);
                    acc[2*k] += a.x; acc[2*k+1] += a.y;
                }
            }
            if (i1 <= last) {
#pragma unroll
                for (int k = 0; k < 4; k++) {
                    float2 a = __half22float2(p1[k]);
                    acc[2*k] += a.x; acc[2*k+1] += a.y;
                }
            }
            if (i2 <= last) {
#pragma unroll
                for (int k = 0; k < 4; k++) {
                    float2 a = __half22float2(p2[k]);
                    acc[2*k] += a.x; acc[2*k+1] += a.y;
                }
            }
            if (i3 <= last) {
#pragma unroll
                for (int k = 0; k < 4; k++) {
                    float2 a = __half22float2(p3[k]);
                    acc[2*k] += a.x; acc[2*k+1] += a.y;
                }
            }
        }
        if (jj == 0) {                          // self-loop, added once
            uint4 qs = u2q[node];
            const __half2* ps = (const __half2*)&qs;
#pragma unroll
            for (int k = 0; k < 4; k++) {
                float2 a = __half22float2(ps[k]);
                acc[2*k] += a.x; acc[2*k+1] += a.y;
            }
        }
#pragma unroll
        for (int k = 0; k < 8; k++) {
            acc[k] += __shfl_xor(acc[k], 1, 64);
            acc[k] += __shfl_xor(acc[k], 2, 64);
            acc[k] += __shfl_xor(acc[k], 4, 64);
        }
        if (jj == 0) {
            float d = dinv[node];
#pragma unroll
            for (int k = 0; k < 8; k++) h[k] = tanhf(d * acc[k] + b2[k]);
            g = batch[node];
            c = 1.0f;
        }
    }
    // stride-8 segmented reduction: base lanes (jj==0) hold 8 consecutive
    // nodes per wave; offsets 8..32 only ever read base lanes.
#pragma unroll
    for (int off = 8; off < 64; off <<= 1) {
        int gn = __shfl_down(g, off, 64);
        float cn = __shfl_down(c, off, 64);
        float hn[8];
#pragma unroll
        for (int k = 0; k < 8; k++) hn[k] = __shfl_down(h[k], off, 64);
        bool take = (lane + off < 64) && (gn == g);
        if (take) {
            c += cn;
#pragma unroll
            for (int k = 0; k < 8; k++) h[k] += hn[k];
        }
    }
    int gprev = __shfl_up(g, 8, 64);
    bool head = valid && (jj == 0) && (lane == 0 || gprev != g);
    if (head) {
#pragma unroll
        for (int k = 0; k < 8; k++) atomicAdd(&pooled[g * 8 + k], h[k]);
        atomicAdd(&cnt[g], c);
    }
}

// Tiny head: out[g] = dot(pooled[g], W3) / max(cnt,1) + b3
__global__ void k_out(const float* __restrict__ pooled, const float* __restrict__ cnt,
                      const float* __restrict__ W3, const float* __restrict__ b3,
                      float* __restrict__ out, int G) {
    int g = blockIdx.x * BLK + threadIdx.x;
    if (g >= G) return;
    float c = fmaxf(cnt[g], 1.0f);
    float t = 0.0f;
#pragma unroll
    for (int k = 0; k < 8; k++) t += pooled[g * 8 + k] * W3[k];
    out[g] = t / c + b3[0];
}

extern "C" void kernel_launch(void* const* d_in, const int* in_sizes, int n_in,
                              void* d_out, int out_size, void* d_ws, size_t ws_size,
                              hipStream_t stream) {
    const float* x    = (const float*)d_in[0];
    const int*   ei   = (const int*)d_in[1];
    const int*   batch= (const int*)d_in[2];
    const float* Wemb = (const float*)d_in[3];
    const float* bemb = (const float*)d_in[4];
    const float* W1   = (const float*)d_in[5];
    const float* b1   = (const float*)d_in[6];
    const float* W2   = (const float*)d_in[7];
    const float* b2   = (const float*)d_in[8];
    const float* W3   = (const float*)d_in[9];
    const float* b3   = (const float*)d_in[10];
    float* out = (float*)d_out;

    const int n = in_sizes[2];        // 100000
    const int E = in_sizes[1] / 2;    // 3200000
    const int G = out_size;           // 1024
    const int* row = ei;
    const int* col = ei + E;
    const int NB = (n + NPB - 1) / NPB;   // 391

    // workspace (4B words): dinv[n] | u1q(8n reserved, 4n used: fp8 16B/node) |
    //   u2h(4n) | rs[n] | re[n] | bucketCnt[NBMX] | pooled[8G] | cnt[G] |
    //   data[NB*CAPB]  (~20.5 MB)
    float* ws    = (float*)d_ws;
    float* dinv  = ws;                       // n
    uint4* u1q   = (uint4*)(ws + n);         // 4n words used (16 fp8/node)
    __half* u2h  = (__half*)(ws + 9 * n);    // 4n words (8 halves/node)
    int* rs      = (int*)(ws + 13 * n);      // n
    int* re      = rs + n;                   // n
    int* bucketCnt = re + n;                 // NBMX
    float* pooled  = (float*)(bucketCnt + NBMX);   // 8G
    float* cnt     = pooled + 8 * G;               // G
    unsigned int* data = (unsigned int*)(cnt + G); // NB*CAPB

    int gridP = (E + CAPS - 1) / CAPS;       // 521 blocks, chunk = 6144
    int gridA = (8 * n + BLK - 1) / BLK;     // 3125 blocks, 8 lanes/node

    // one memset zeroes bucketCnt + pooled + cnt (contiguous)
    hipMemsetAsync(bucketCnt, 0, (NBMX + 8 * G + G) * sizeof(int), stream);
    k_place<<<gridP, PBLK, 0, stream>>>((const int4*)row, (const int4*)col,
                                        bucketCnt, data, E, NB);
    k_sort_node1<<<NB, SBLK, 0, stream>>>(data, bucketCnt, (const float4*)x,
                                          Wemb, bemb, W1, rs, re, dinv, u1q, n);
    k_agg1<<<gridA, BLK, 0, stream>>>(data, rs, re, u1q,
                                      dinv, b1, W2, (uint4*)u2h, n);
    k_agg2_pool<<<gridA, BLK, 0, stream>>>(data, rs, re,
                                           (const uint4*)u2h, dinv, b2,
                                           batch, pooled, cnt, n);
    k_out<<<(G + BLK - 1) / BLK, BLK, 0, stream>>>(pooled, cnt, W3, b3, out, G);
}

// Round 7
// 183.101 us; speedup vs baseline: 1.1136x; 1.0709x over previous
//
#include <hip/hip_runtime.h>
#include <hip/hip_fp16.h>

// GCN: N=100000 nodes (4 feats), E=3.2M edges, G=1024 graphs.
// out = mean-pool(tanh(gcn2(tanh(gcn1(embed(x)))))) @ W3.T + b3
//
// gcn_conv rewritten: u[i] = (h[i] @ W^T) * dinv[i];
// out[c] = dinv[c] * (sum_{edges r->c} u[r] + u[c]) + b   (self-loop folded in)
//
// R19 (resubmit; R6 was an infra failure): unbundled R17. KEEP: (a) x4
// lane-group-replicated LDS bin counters in both rank passes (4x less
// same-bin atomic serialization; R4 arith showed sort kernels -15-20us),
// (b) stageB direct copy-out (no binary search). DROP: fused k_out +
// per-block __threadfence (R4: +35us convoy on k_agg2_pool). Aggs stay
// R16 4-lane (R5 proved 8-lane/4-slot prefetch regresses: dup epilogue +
// wasted clamped gathers). R15b: u1 fp8 e4m3 (x64, cvt_pk), ONE uint4
// gather/edge. Walls: harness 0xAA re-poison ~44us fixed; fills cap top-5.

constexpr int BLK  = 256;
constexpr int NPB  = 256;            // dst nodes per bucket (dloc = 8 bits)
constexpr int NBMX = 512;            // padded bin count (NB = 391)
constexpr int CAPB = 9216;           // slots/bucket; mean 8184, sigma ~90
constexpr int PBLK = 512;            // k_place block size
constexpr int CAPS = 6144;           // k_place chunk = PBLK * EPT
constexpr int EPT  = 12;             // edges/thread in k_place
constexpr int SBLK = 512;            // k_sort block size
constexpr int NIT4 = 5;              // uint4 iters: ceil(CAPB/(SBLK*4))
constexpr float S8 = 64.0f;          // fp8 scale for u1 messages

// Single-pass placement, ONE LDS-atomic pass (x4 replicated bins):
// o = atomicAdd(&pos[rep][b],1) is both offset and histogram; scan merges
// replicas -> sstart + per-replica bases; reserve global space; stage
// (entry + bucket id); direct-lookup copy-out. entry = (dloc<<17) | src.
__global__ void k_place(const int4* __restrict__ row4, const int4* __restrict__ col4,
                        int* __restrict__ bucketCnt, unsigned int* __restrict__ data,
                        int E, int NB) {
    __shared__ unsigned int stage[CAPS];                    // 24.6 KB
    __shared__ unsigned short stageB[CAPS];                 // 12.3 KB
    __shared__ int pos[4][NBMX];                            // 8 KB
    __shared__ int sstart[NBMX], lbase[NBMX];               // 4 KB
    __shared__ int wsum[8];
    int t = threadIdx.x;                        // 0..511
    int lane = t & 63, w = t >> 6;
    int rep = (lane >> 4) & 3;                  // replica by lane group
    int begin = blockIdx.x * CAPS;
    int end = min(E, begin + CAPS);
    int csize = end - begin;                    // multiple of 4
    int q0 = begin >> 2, q1 = end >> 2;
#pragma unroll
    for (int rr = 0; rr < 4; rr++) pos[rr][t] = 0;
    __syncthreads();
    unsigned int ent[EPT];
    int meta[EPT];
#pragma unroll
    for (int it = 0; it < EPT / 4; it++) {
        int i = q0 + t + it * PBLK;
        bool ok = i < q1;
        int4 c = ok ? col4[i] : make_int4(0, 0, 0, 0);
        int4 r = ok ? row4[i] : make_int4(0, 0, 0, 0);
#pragma unroll
        for (int k = 0; k < 4; k++) {
            int cc = ((const int*)&c)[k];
            int rr = ((const int*)&r)[k];
            int b = cc >> 8;
            int o = ok ? atomicAdd(&pos[rep][b], 1) : 0;
            ent[it * 4 + k] = ((unsigned int)(cc & 255) << 17) | (unsigned int)rr;
            // meta = (rep<<22) | (b<<13) | o   (b<512: 9b, o<6144: 13b)
            meta[it * 4 + k] = ok ? ((rep << 22) | (b << 13) | o) : -1;
        }
    }
    __syncthreads();
    // scan 512 bins, thread owns bin t; merge 4 replicas
    int p0 = pos[0][t], p1 = pos[1][t], p2 = pos[2][t], p3 = pos[3][t];
    int v = p0 + p1 + p2 + p3;
    int sc = v;
#pragma unroll
    for (int off = 1; off < 64; off <<= 1) {
        int o = __shfl_up(sc, off, 64);
        if (lane >= off) sc += o;
    }
    if (lane == 63) wsum[w] = sc;
    __syncthreads();
    int pre = 0;
#pragma unroll
    for (int i = 0; i < 8; i++) if (i < w) pre += wsum[i];
    int excl = sc + pre - v;
    sstart[t] = excl;
    lbase[t] = v ? atomicAdd(&bucketCnt[t], v) : 0;
    // per-replica base offsets within bin t (overwrite counters)
    pos[0][t] = 0;
    pos[1][t] = p0;
    pos[2][t] = p0 + p1;
    pos[3][t] = p0 + p1 + p2;
    __syncthreads();
#pragma unroll
    for (int k = 0; k < EPT; k++) {
        int m = meta[k];
        if (m >= 0) {
            int rr = m >> 22;
            int b  = (m >> 13) & 0x1FF;
            int o  = m & 0x1FFF;
            int idx = sstart[b] + pos[rr][b] + o;
            stage[idx]  = ent[k];
            stageB[idx] = (unsigned short)b;
        }
    }
    __syncthreads();
    for (int k = t; k < csize; k += PBLK) {
        int b = stageB[k];
        data[(unsigned int)b * CAPB + (unsigned int)(lbase[b] + (k - sstart[b]))] = stage[k];
    }
}

// Per-bucket one-pass counting sort (edges in registers via uint4 loads,
// x4 replicated bins, scatter straight to the L2-resident bucket region)
// + dinv + rs/re + fused node1 (u1 encoded fp8 e4m3 x64). BLK=512.
__global__ void k_sort_node1(unsigned int* __restrict__ data,
                             const int* __restrict__ bucketCnt,
                             const float4* __restrict__ x,
                             const float* __restrict__ Wemb, const float* __restrict__ bemb,
                             const float* __restrict__ W1,
                             int* __restrict__ rs, int* __restrict__ re,
                             float* __restrict__ dinv, uint4* __restrict__ u1q, int n) {
    __shared__ int pos[4][NPB], startl[NPB];
    __shared__ int wsum[4];
    int b = blockIdx.x;
    int t = threadIdx.x;                        // 0..511
    int lane = t & 63;
    int rep = (lane >> 4) & 3;
    int base = b * CAPB;
    int cnt = min(bucketCnt[b], CAPB);
    ((int*)pos)[t] = 0;
    ((int*)pos)[t + SBLK] = 0;                  // 4*256 = 1024 ints
    __syncthreads();
    const uint4* data4 = (const uint4*)(data + base);   // base = b*9216, 16B aligned
    unsigned int ent[NIT4 * 4];                 // src (17 bits)
    int off[NIT4 * 4];                          // (rep<<22)|(dloc<<14)|o
#pragma unroll
    for (int it = 0; it < NIT4; it++) {
        int i4 = t + it * SBLK;                 // quad index
        int i = i4 * 4;
        uint4 p4 = (i < cnt) ? data4[i4] : make_uint4(0, 0, 0, 0);
#pragma unroll
        for (int k = 0; k < 4; k++) {
            int idx = it * 4 + k;
            if (i + k < cnt) {
                unsigned int p = ((const unsigned int*)&p4)[k];
                int dloc = (int)(p >> 17);
                int o = atomicAdd(&pos[rep][dloc], 1);
                ent[idx] = p & 0x1FFFF;
                off[idx] = (rep << 22) | (dloc << 14) | o;
            } else off[idx] = -1;
        }
    }
    __syncthreads();
    int node = b * NPB + t;
    float d = 0.0f;
    if (t < NPB) {
        int w = t >> 6;
        int p0 = pos[0][t], p1 = pos[1][t], p2 = pos[2][t], p3 = pos[3][t];
        int v = p0 + p1 + p2 + p3;
        int sc = v;
#pragma unroll
        for (int o = 1; o < 64; o <<= 1) {
            int s = __shfl_up(sc, o, 64);
            if (lane >= o) sc += s;
        }
        if (lane == 63) wsum[w] = sc;
        __syncthreads();
        int pre = 0;
#pragma unroll
        for (int i = 0; i < 4; i++) if (i < w) pre += wsum[i];
        int excl = sc + pre - v;
        startl[t] = excl;
        pos[0][t] = 0;
        pos[1][t] = p0;
        pos[2][t] = p0 + p1;
        pos[3][t] = p0 + p1 + p2;
        if (node < n) {
            rs[node] = base + excl;
            re[node] = base + excl + v;
            d = rsqrtf((float)v + 1.0f);        // +1 self-loop
            dinv[node] = d;
        }
    } else {
        __syncthreads();
    }
    __syncthreads();
#pragma unroll
    for (int it = 0; it < NIT4 * 4; it++) {
        int m = off[it];
        if (m >= 0) {
            int rr = (m >> 22) & 3;
            int dl = (m >> 14) & 255;
            int o  = m & 0x3FFF;
            data[base + startl[dl] + pos[rr][dl] + o] = ent[it];
        }
    }
    if (t < NPB && node < n) {
        float4 xi = x[node];
        float h0[7];
#pragma unroll
        for (int j = 0; j < 4; j++) h0[j] = xi.x * Wemb[j] + bemb[j];
        h0[4] = xi.y; h0[5] = xi.z; h0[6] = xi.w;
        float s[16];
#pragma unroll
        for (int f = 0; f < 16; f++) {
            float tt = 0.0f;
#pragma unroll
            for (int j = 0; j < 7; j++) tt += h0[j] * W1[f * 7 + j];
            s[f] = tt * d * S8;                 // fp8 scale folded here
        }
        unsigned int w0, w1, w2, w3;
        w0 = __builtin_amdgcn_cvt_pk_fp8_f32(s[0],  s[1],  0,  false);
        w0 = __builtin_amdgcn_cvt_pk_fp8_f32(s[2],  s[3],  w0, true);
        w1 = __builtin_amdgcn_cvt_pk_fp8_f32(s[4],  s[5],  0,  false);
        w1 = __builtin_amdgcn_cvt_pk_fp8_f32(s[6],  s[7],  w1, true);
        w2 = __builtin_amdgcn_cvt_pk_fp8_f32(s[8],  s[9],  0,  false);
        w2 = __builtin_amdgcn_cvt_pk_fp8_f32(s[10], s[11], w2, true);
        w3 = __builtin_amdgcn_cvt_pk_fp8_f32(s[12], s[13], 0,  false);
        w3 = __builtin_amdgcn_cvt_pk_fp8_f32(s[14], s[15], w3, true);
        u1q[node] = make_uint4(w0, w1, w2, w3);
    }
}

typedef float vfloat2 __attribute__((vector_size(8)));   // cvt_pk_f32_fp8 return type

// fp8 e4m3 uint4 (16 msgs) decode-accumulate into f32[16]
__device__ __forceinline__ void dec16_add(uint4 q, float* acc) {
#pragma unroll
    for (int w = 0; w < 4; w++) {
        unsigned int u = ((const unsigned int*)&q)[w];
        vfloat2 lo = __builtin_amdgcn_cvt_pk_f32_fp8(u, false);
        vfloat2 hi = __builtin_amdgcn_cvt_pk_f32_fp8(u, true);
        acc[4 * w + 0] += lo[0]; acc[4 * w + 1] += lo[1];
        acc[4 * w + 2] += hi[0]; acc[4 * w + 3] += hi[1];
    }
}

// Layer 1: 4 adjacent lanes/node, lane j takes edges s+j, s+j+4, ...
// ONE uint4 (16 fp8) gather per edge; partials combined via shfl_xor(1,2).
// Epilogue (all 4 lanes compute, j==0 stores): h1 = tanh(dinv/S8*acc+b1);
// u2h = fp16((h1 @ W2^T) * dinv), one uint4 store.
__global__ void k_agg1(const unsigned int* __restrict__ sorted,
                       const int* __restrict__ rs, const int* __restrict__ re,
                       const uint4* __restrict__ u1q, const float* __restrict__ dinv,
                       const float* __restrict__ b1, const float* __restrict__ W2,
                       uint4* __restrict__ u2q, int n) {
    int tt = blockIdx.x * BLK + threadIdx.x;
    int node = tt >> 2;
    int j = tt & 3;
    if (node >= n) return;
    int s = rs[node], e = re[node];
    float acc[16];
#pragma unroll
    for (int k = 0; k < 16; k++) acc[k] = 0.0f;
    int i = s + j;
    for (; i + 4 < e; i += 8) {                 // 2 gathers in flight
        uint4 q0 = u1q[sorted[i]];
        uint4 q1 = u1q[sorted[i + 4]];
        dec16_add(q0, acc);
        dec16_add(q1, acc);
    }
    if (i < e) {
        uint4 q = u1q[sorted[i]];
        dec16_add(q, acc);
    }
    if (j == 0) {                               // self-loop term, added once
        uint4 qs = u1q[node];
        dec16_add(qs, acc);
    }
#pragma unroll
    for (int k = 0; k < 16; k++) {
        acc[k] += __shfl_xor(acc[k], 1, 64);
        acc[k] += __shfl_xor(acc[k], 2, 64);
    }
    float d = dinv[node];
    float dS = d * (1.0f / S8);                 // undo fp8 scale
    float h1[16];
#pragma unroll
    for (int k = 0; k < 16; k++) h1[k] = tanhf(dS * acc[k] + b1[k]);
    float r[8];
#pragma unroll
    for (int g = 0; g < 8; g++) {
        float ttv = 0.0f;
#pragma unroll
        for (int k = 0; k < 16; k++) ttv += h1[k] * W2[g * 16 + k];
        r[g] = ttv * d;
    }
    if (j == 0) {
        union { __half2 h2[4]; uint4 u4; } pk;
#pragma unroll
        for (int q = 0; q < 4; q++) pk.h2[q] = __floats2half2_rn(r[2 * q], r[2 * q + 1]);
        u2q[node] = pk.u4;
    }
}

// Layer 2 + POOL fused: 4 adjacent lanes/node (16 nodes/wave), uint4 gathers;
// partials combined via shfl_xor(1,2); h2 in f32 registers on base lanes;
// stride-4 wave-segmented reduction over sorted batch (offsets 4..32),
// segment heads atomicAdd 8 features + count into pooled/cnt.
__global__ void k_agg2_pool(const unsigned int* __restrict__ sorted,
                            const int* __restrict__ rs, const int* __restrict__ re,
                            const uint4* __restrict__ u2q, const float* __restrict__ dinv,
                            const float* __restrict__ b2, const int* __restrict__ batch,
                            float* __restrict__ pooled, float* __restrict__ cnt, int n) {
    int tt = blockIdx.x * BLK + threadIdx.x;
    int node = tt >> 2;
    int j = tt & 3;
    int lane = threadIdx.x & 63;
    bool valid = node < n;
    float h[8];
#pragma unroll
    for (int k = 0; k < 8; k++) h[k] = 0.0f;
    int g = -1;
    float c = 0.0f;
    if (valid) {
        int s = rs[node], e = re[node];
        float acc[8];
#pragma unroll
        for (int k = 0; k < 8; k++) acc[k] = 0.0f;
        int i = s + j;
        for (; i + 4 < e; i += 8) {
            uint4 q0 = u2q[sorted[i]];
            uint4 q1 = u2q[sorted[i + 4]];
            const __half2* p0 = (const __half2*)&q0;
            const __half2* p1 = (const __half2*)&q1;
#pragma unroll
            for (int k = 0; k < 4; k++) {
                float2 a0 = __half22float2(p0[k]);
                float2 a1 = __half22float2(p1[k]);
                acc[2*k]   += a0.x + a1.x;
                acc[2*k+1] += a0.y + a1.y;
            }
        }
        if (i < e) {
            uint4 q = u2q[sorted[i]];
            const __half2* p = (const __half2*)&q;
#pragma unroll
            for (int k = 0; k < 4; k++) {
                float2 a = __half22float2(p[k]);
                acc[2*k]   += a.x;
                acc[2*k+1] += a.y;
            }
        }
        if (j == 0) {                           // self-loop, added once
            uint4 qs = u2q[node];
            const __half2* ps = (const __half2*)&qs;
#pragma unroll
            for (int k = 0; k < 4; k++) {
                float2 a = __half22float2(ps[k]);
                acc[2*k]   += a.x;
                acc[2*k+1] += a.y;
            }
        }
#pragma unroll
        for (int k = 0; k < 8; k++) {
            acc[k] += __shfl_xor(acc[k], 1, 64);
            acc[k] += __shfl_xor(acc[k], 2, 64);
        }
        if (j == 0) {
            float d = dinv[node];
#pragma unroll
            for (int k = 0; k < 8; k++) h[k] = tanhf(d * acc[k] + b2[k]);
            g = batch[node];
            c = 1.0f;
        }
    }
    // stride-4 segmented reduction: base lanes (j==0) hold 16 consecutive
    // nodes per wave; offsets 4..32 only ever read base lanes.
#pragma unroll
    for (int off = 4; off < 64; off <<= 1) {
        int gn = __shfl_down(g, off, 64);
        float cn = __shfl_down(c, off, 64);
        float hn[8];
#pragma unroll
        for (int k = 0; k < 8; k++) hn[k] = __shfl_down(h[k], off, 64);
        bool take = (lane + off < 64) && (gn == g);
        if (take) {
            c += cn;
#pragma unroll
            for (int k = 0; k < 8; k++) h[k] += hn[k];
        }
    }
    int gprev = __shfl_up(g, 4, 64);
    bool head = valid && (j == 0) && (lane == 0 || gprev != g);
    if (head) {
#pragma unroll
        for (int k = 0; k < 8; k++) atomicAdd(&pooled[g * 8 + k], h[k]);
        atomicAdd(&cnt[g], c);
    }
}

// Tiny head: out[g] = dot(pooled[g], W3) / max(cnt,1) + b3
__global__ void k_out(const float* __restrict__ pooled, const float* __restrict__ cnt,
                      const float* __restrict__ W3, const float* __restrict__ b3,
                      float* __restrict__ out, int G) {
    int g = blockIdx.x * BLK + threadIdx.x;
    if (g >= G) return;
    float c = fmaxf(cnt[g], 1.0f);
    float t = 0.0f;
#pragma unroll
    for (int k = 0; k < 8; k++) t += pooled[g * 8 + k] * W3[k];
    out[g] = t / c + b3[0];
}

extern "C" void kernel_launch(void* const* d_in, const int* in_sizes, int n_in,
                              void* d_out, int out_size, void* d_ws, size_t ws_size,
                              hipStream_t stream) {
    const float* x    = (const float*)d_in[0];
    const int*   ei   = (const int*)d_in[1];
    const int*   batch= (const int*)d_in[2];
    const float* Wemb = (const float*)d_in[3];
    const float* bemb = (const float*)d_in[4];
    const float* W1   = (const float*)d_in[5];
    const float* b1   = (const float*)d_in[6];
    const float* W2   = (const float*)d_in[7];
    const float* b2   = (const float*)d_in[8];
    const float* W3   = (const float*)d_in[9];
    const float* b3   = (const float*)d_in[10];
    float* out = (float*)d_out;

    const int n = in_sizes[2];        // 100000
    const int E = in_sizes[1] / 2;    // 3200000
    const int G = out_size;           // 1024
    const int* row = ei;
    const int* col = ei + E;
    const int NB = (n + NPB - 1) / NPB;   // 391

    // workspace (4B words): dinv[n] | u1q(8n reserved, 4n used: fp8 16B/node) |
    //   u2h(4n) | rs[n] | re[n] | bucketCnt[NBMX] | pooled[8G] | cnt[G] |
    //   data[NB*CAPB]  (~20.5 MB)
    float* ws    = (float*)d_ws;
    float* dinv  = ws;                       // n
    uint4* u1q   = (uint4*)(ws + n);         // 4n words used (16 fp8/node)
    __half* u2h  = (__half*)(ws + 9 * n);    // 4n words (8 halves/node)
    int* rs      = (int*)(ws + 13 * n);      // n
    int* re      = rs + n;                   // n
    int* bucketCnt = re + n;                 // NBMX
    float* pooled  = (float*)(bucketCnt + NBMX);   // 8G
    float* cnt     = pooled + 8 * G;               // G
    unsigned int* data = (unsigned int*)(cnt + G); // NB*CAPB

    int gridP = (E + CAPS - 1) / CAPS;       // 521 blocks, chunk = 6144
    int gridA = (4 * n + BLK - 1) / BLK;     // 1563 blocks, 4 lanes/node

    // one memset zeroes bucketCnt + pooled + cnt (contiguous)
    hipMemsetAsync(bucketCnt, 0, (NBMX + 8 * G + G) * sizeof(int), stream);
    k_place<<<gridP, PBLK, 0, stream>>>((const int4*)row, (const int4*)col,
                                        bucketCnt, data, E, NB);
    k_sort_node1<<<NB, SBLK, 0, stream>>>(data, bucketCnt, (const float4*)x,
                                          Wemb, bemb, W1, rs, re, dinv, u1q, n);
    k_agg1<<<gridA, BLK, 0, stream>>>(data, rs, re, u1q,
                                      dinv, b1, W2, (uint4*)u2h, n);
    k_agg2_pool<<<gridA, BLK, 0, stream>>>(data, rs, re,
                                           (const uint4*)u2h, dinv, b2,
                                           batch, pooled, cnt, n);
    k_out<<<(G + BLK - 1) / BLK, BLK, 0, stream>>>(pooled, cnt, W3, b3, out, G);
}

// Round 8
// 179.972 us; speedup vs baseline: 1.1330x; 1.0174x over previous
//
#include <hip/hip_runtime.h>
#include <hip/hip_fp16.h>

// GCN: N=100000 nodes (4 feats), E=3.2M edges, G=1024 graphs.
// out = mean-pool(tanh(gcn2(tanh(gcn1(embed(x)))))) @ W3.T + b3
//
// gcn_conv rewritten: u[i] = (h[i] @ W^T) * dinv[i];
// out[c] = dinv[c] * (sum_{edges r->c} u[r] + u[c]) + b   (self-loop folded in)
//
// R20: three micro-levers on the measured-183.1 R19 base:
// (1) k_sort rank replication x4 -> x8 (lane>>3 groups; pos = 8KB LDS);
// (2) aggs: 4 gathers in flight within the 4-lane layout (no clamp waste,
//     no dup epilogue -- fixes R5's confound; mean 8 edges/lane -> 2 deep
//     iters instead of 4 latency exposures);
// (3) per-node self/dinv/batch loads hoisted above the edge loop
//     (exec-predicated) so their latency hides under the gather chain.
// R19: x4-replicated rank bins both passes + stageB direct copy-out.
// R16: 4-lane aggs + shfl_xor combine. R15b: u1 fp8 e4m3 (x64, cvt_pk),
// ONE uint4 gather/edge. Walls: harness 0xAA re-poison ~44us fixed.

constexpr int BLK  = 256;
constexpr int NPB  = 256;            // dst nodes per bucket (dloc = 8 bits)
constexpr int NBMX = 512;            // padded bin count (NB = 391)
constexpr int CAPB = 9216;           // slots/bucket; mean 8184, sigma ~90
constexpr int PBLK = 512;            // k_place block size
constexpr int CAPS = 6144;           // k_place chunk = PBLK * EPT
constexpr int EPT  = 12;             // edges/thread in k_place
constexpr int SBLK = 512;            // k_sort block size
constexpr int NIT4 = 5;              // uint4 iters: ceil(CAPB/(SBLK*4))
constexpr float S8 = 64.0f;          // fp8 scale for u1 messages

// Single-pass placement, ONE LDS-atomic pass (x4 replicated bins):
// o = atomicAdd(&pos[rep][b],1) is both offset and histogram; scan merges
// replicas -> sstart + per-replica bases; reserve global space; stage
// (entry + bucket id); direct-lookup copy-out. entry = (dloc<<17) | src.
__global__ void k_place(const int4* __restrict__ row4, const int4* __restrict__ col4,
                        int* __restrict__ bucketCnt, unsigned int* __restrict__ data,
                        int E, int NB) {
    __shared__ unsigned int stage[CAPS];                    // 24.6 KB
    __shared__ unsigned short stageB[CAPS];                 // 12.3 KB
    __shared__ int pos[4][NBMX];                            // 8 KB
    __shared__ int sstart[NBMX], lbase[NBMX];               // 4 KB
    __shared__ int wsum[8];
    int t = threadIdx.x;                        // 0..511
    int lane = t & 63, w = t >> 6;
    int rep = (lane >> 4) & 3;                  // replica by lane group
    int begin = blockIdx.x * CAPS;
    int end = min(E, begin + CAPS);
    int csize = end - begin;                    // multiple of 4
    int q0 = begin >> 2, q1 = end >> 2;
#pragma unroll
    for (int rr = 0; rr < 4; rr++) pos[rr][t] = 0;
    __syncthreads();
    unsigned int ent[EPT];
    int meta[EPT];
#pragma unroll
    for (int it = 0; it < EPT / 4; it++) {
        int i = q0 + t + it * PBLK;
        bool ok = i < q1;
        int4 c = ok ? col4[i] : make_int4(0, 0, 0, 0);
        int4 r = ok ? row4[i] : make_int4(0, 0, 0, 0);
#pragma unroll
        for (int k = 0; k < 4; k++) {
            int cc = ((const int*)&c)[k];
            int rr = ((const int*)&r)[k];
            int b = cc >> 8;
            int o = ok ? atomicAdd(&pos[rep][b], 1) : 0;
            ent[it * 4 + k] = ((unsigned int)(cc & 255) << 17) | (unsigned int)rr;
            // meta = (rep<<22) | (b<<13) | o   (b<512: 9b, o<6144: 13b)
            meta[it * 4 + k] = ok ? ((rep << 22) | (b << 13) | o) : -1;
        }
    }
    __syncthreads();
    // scan 512 bins, thread owns bin t; merge 4 replicas
    int p0 = pos[0][t], p1 = pos[1][t], p2 = pos[2][t], p3 = pos[3][t];
    int v = p0 + p1 + p2 + p3;
    int sc = v;
#pragma unroll
    for (int off = 1; off < 64; off <<= 1) {
        int o = __shfl_up(sc, off, 64);
        if (lane >= off) sc += o;
    }
    if (lane == 63) wsum[w] = sc;
    __syncthreads();
    int pre = 0;
#pragma unroll
    for (int i = 0; i < 8; i++) if (i < w) pre += wsum[i];
    int excl = sc + pre - v;
    sstart[t] = excl;
    lbase[t] = v ? atomicAdd(&bucketCnt[t], v) : 0;
    // per-replica base offsets within bin t (overwrite counters)
    pos[0][t] = 0;
    pos[1][t] = p0;
    pos[2][t] = p0 + p1;
    pos[3][t] = p0 + p1 + p2;
    __syncthreads();
#pragma unroll
    for (int k = 0; k < EPT; k++) {
        int m = meta[k];
        if (m >= 0) {
            int rr = m >> 22;
            int b  = (m >> 13) & 0x1FF;
            int o  = m & 0x1FFF;
            int idx = sstart[b] + pos[rr][b] + o;
            stage[idx]  = ent[k];
            stageB[idx] = (unsigned short)b;
        }
    }
    __syncthreads();
    for (int k = t; k < csize; k += PBLK) {
        int b = stageB[k];
        data[(unsigned int)b * CAPB + (unsigned int)(lbase[b] + (k - sstart[b]))] = stage[k];
    }
}

// Per-bucket one-pass counting sort (edges in registers via uint4 loads,
// x8 replicated bins, scatter straight to the L2-resident bucket region)
// + dinv + rs/re + fused node1 (u1 encoded fp8 e4m3 x64). BLK=512.
__global__ void k_sort_node1(unsigned int* __restrict__ data,
                             const int* __restrict__ bucketCnt,
                             const float4* __restrict__ x,
                             const float* __restrict__ Wemb, const float* __restrict__ bemb,
                             const float* __restrict__ W1,
                             int* __restrict__ rs, int* __restrict__ re,
                             float* __restrict__ dinv, uint4* __restrict__ u1q, int n) {
    __shared__ int pos[8][NPB], startl[NPB];    // 8 KB + 1 KB
    __shared__ int wsum[4];
    int b = blockIdx.x;
    int t = threadIdx.x;                        // 0..511
    int lane = t & 63;
    int rep = (lane >> 3) & 7;                  // x8 replica by 8-lane group
    int base = b * CAPB;
    int cnt = min(bucketCnt[b], CAPB);
#pragma unroll
    for (int z = 0; z < 4; z++) ((int*)pos)[t + z * SBLK] = 0;   // 8*256 ints
    __syncthreads();
    const uint4* data4 = (const uint4*)(data + base);   // base = b*9216, 16B aligned
    unsigned int ent[NIT4 * 4];                 // src (17 bits)
    int off[NIT4 * 4];                          // (rep<<22)|(dloc<<14)|o
#pragma unroll
    for (int it = 0; it < NIT4; it++) {
        int i4 = t + it * SBLK;                 // quad index
        int i = i4 * 4;
        uint4 p4 = (i < cnt) ? data4[i4] : make_uint4(0, 0, 0, 0);
#pragma unroll
        for (int k = 0; k < 4; k++) {
            int idx = it * 4 + k;
            if (i + k < cnt) {
                unsigned int p = ((const unsigned int*)&p4)[k];
                int dloc = (int)(p >> 17);
                int o = atomicAdd(&pos[rep][dloc], 1);
                ent[idx] = p & 0x1FFFF;
                off[idx] = (rep << 22) | (dloc << 14) | o;
            } else off[idx] = -1;
        }
    }
    __syncthreads();
    int node = b * NPB + t;
    float d = 0.0f;
    if (t < NPB) {
        int w = t >> 6;
        int p[8];
        int v = 0;
#pragma unroll
        for (int r = 0; r < 8; r++) { p[r] = pos[r][t]; v += p[r]; }
        int sc = v;
#pragma unroll
        for (int o = 1; o < 64; o <<= 1) {
            int s = __shfl_up(sc, o, 64);
            if (lane >= o) sc += s;
        }
        if (lane == 63) wsum[w] = sc;
        __syncthreads();
        int pre = 0;
#pragma unroll
        for (int i = 0; i < 4; i++) if (i < w) pre += wsum[i];
        int excl = sc + pre - v;
        startl[t] = excl;
        int run = 0;
#pragma unroll
        for (int r = 0; r < 8; r++) { pos[r][t] = run; run += p[r]; }
        if (node < n) {
            rs[node] = base + excl;
            re[node] = base + excl + v;
            d = rsqrtf((float)v + 1.0f);        // +1 self-loop
            dinv[node] = d;
        }
    } else {
        __syncthreads();
    }
    __syncthreads();
#pragma unroll
    for (int it = 0; it < NIT4 * 4; it++) {
        int m = off[it];
        if (m >= 0) {
            int rr = (m >> 22) & 7;
            int dl = (m >> 14) & 255;
            int o  = m & 0x3FFF;
            data[base + startl[dl] + pos[rr][dl] + o] = ent[it];
        }
    }
    if (t < NPB && node < n) {
        float4 xi = x[node];
        float h0[7];
#pragma unroll
        for (int j = 0; j < 4; j++) h0[j] = xi.x * Wemb[j] + bemb[j];
        h0[4] = xi.y; h0[5] = xi.z; h0[6] = xi.w;
        float s[16];
#pragma unroll
        for (int f = 0; f < 16; f++) {
            float tt = 0.0f;
#pragma unroll
            for (int j = 0; j < 7; j++) tt += h0[j] * W1[f * 7 + j];
            s[f] = tt * d * S8;                 // fp8 scale folded here
        }
        unsigned int w0, w1, w2, w3;
        w0 = __builtin_amdgcn_cvt_pk_fp8_f32(s[0],  s[1],  0,  false);
        w0 = __builtin_amdgcn_cvt_pk_fp8_f32(s[2],  s[3],  w0, true);
        w1 = __builtin_amdgcn_cvt_pk_fp8_f32(s[4],  s[5],  0,  false);
        w1 = __builtin_amdgcn_cvt_pk_fp8_f32(s[6],  s[7],  w1, true);
        w2 = __builtin_amdgcn_cvt_pk_fp8_f32(s[8],  s[9],  0,  false);
        w2 = __builtin_amdgcn_cvt_pk_fp8_f32(s[10], s[11], w2, true);
        w3 = __builtin_amdgcn_cvt_pk_fp8_f32(s[12], s[13], 0,  false);
        w3 = __builtin_amdgcn_cvt_pk_fp8_f32(s[14], s[15], w3, true);
        u1q[node] = make_uint4(w0, w1, w2, w3);
    }
}

typedef float vfloat2 __attribute__((vector_size(8)));   // cvt_pk_f32_fp8 return type

// fp8 e4m3 uint4 (16 msgs) decode-accumulate into f32[16]
__device__ __forceinline__ void dec16_add(uint4 q, float* acc) {
#pragma unroll
    for (int w = 0; w < 4; w++) {
        unsigned int u = ((const unsigned int*)&q)[w];
        vfloat2 lo = __builtin_amdgcn_cvt_pk_f32_fp8(u, false);
        vfloat2 hi = __builtin_amdgcn_cvt_pk_f32_fp8(u, true);
        acc[4 * w + 0] += lo[0]; acc[4 * w + 1] += lo[1];
        acc[4 * w + 2] += hi[0]; acc[4 * w + 3] += hi[1];
    }
}

// Layer 1: 4 adjacent lanes/node, lane j takes edges s+j, s+j+4, ...
// 4 gathers in flight (4-deep main loop, then 2-deep, then single);
// self/dinv loads hoisted above the loop (predicated) to issue early.
// Partials via shfl_xor(1,2). Epilogue (all 4 lanes compute, j==0 stores):
// u2h = fp16((tanh(dinv/S8*acc+b1) @ W2^T) * dinv), one uint4 store.
__global__ void k_agg1(const unsigned int* __restrict__ sorted,
                       const int* __restrict__ rs, const int* __restrict__ re,
                       const uint4* __restrict__ u1q, const float* __restrict__ dinv,
                       const float* __restrict__ b1, const float* __restrict__ W2,
                       uint4* __restrict__ u2q, int n) {
    int tt = blockIdx.x * BLK + threadIdx.x;
    int node = tt >> 2;
    int j = tt & 3;
    if (node >= n) return;
    int s = rs[node], e = re[node];
    float d = dinv[node];                       // hoisted: issues early
    uint4 qs = make_uint4(0, 0, 0, 0);
    if (j == 0) qs = u1q[node];                 // hoisted self-loop load
    float acc[16];
#pragma unroll
    for (int k = 0; k < 16; k++) acc[k] = 0.0f;
    int i = s + j;
    for (; i + 12 < e; i += 16) {               // 4 gathers in flight
        uint4 q0 = u1q[sorted[i]];
        uint4 q1 = u1q[sorted[i + 4]];
        uint4 q2 = u1q[sorted[i + 8]];
        uint4 q3 = u1q[sorted[i + 12]];
        dec16_add(q0, acc);
        dec16_add(q1, acc);
        dec16_add(q2, acc);
        dec16_add(q3, acc);
    }
    for (; i + 4 < e; i += 8) {                 // 2 in flight
        uint4 q0 = u1q[sorted[i]];
        uint4 q1 = u1q[sorted[i + 4]];
        dec16_add(q0, acc);
        dec16_add(q1, acc);
    }
    if (i < e) {
        uint4 q = u1q[sorted[i]];
        dec16_add(q, acc);
    }
    if (j == 0) dec16_add(qs, acc);             // self-loop term, added once
#pragma unroll
    for (int k = 0; k < 16; k++) {
        acc[k] += __shfl_xor(acc[k], 1, 64);
        acc[k] += __shfl_xor(acc[k], 2, 64);
    }
    float dS = d * (1.0f / S8);                 // undo fp8 scale
    float h1[16];
#pragma unroll
    for (int k = 0; k < 16; k++) h1[k] = tanhf(dS * acc[k] + b1[k]);
    float r[8];
#pragma unroll
    for (int g = 0; g < 8; g++) {
        float ttv = 0.0f;
#pragma unroll
        for (int k = 0; k < 16; k++) ttv += h1[k] * W2[g * 16 + k];
        r[g] = ttv * d;
    }
    if (j == 0) {
        union { __half2 h2[4]; uint4 u4; } pk;
#pragma unroll
        for (int q = 0; q < 4; q++) pk.h2[q] = __floats2half2_rn(r[2 * q], r[2 * q + 1]);
        u2q[node] = pk.u4;
    }
}

__device__ __forceinline__ void h16_add(uint4 q, float* acc) {
    const __half2* p = (const __half2*)&q;
#pragma unroll
    for (int k = 0; k < 4; k++) {
        float2 a = __half22float2(p[k]);
        acc[2 * k]     += a.x;
        acc[2 * k + 1] += a.y;
    }
}

// Layer 2 + POOL fused: 4 adjacent lanes/node (16 nodes/wave), 4 gathers in
// flight; self/dinv/batch hoisted; partials via shfl_xor(1,2); h2 on base
// lanes; stride-4 wave-segmented reduction over sorted batch (offsets
// 4..32), segment heads atomicAdd 8 features + count into pooled/cnt.
__global__ void k_agg2_pool(const unsigned int* __restrict__ sorted,
                            const int* __restrict__ rs, const int* __restrict__ re,
                            const uint4* __restrict__ u2q, const float* __restrict__ dinv,
                            const float* __restrict__ b2, const int* __restrict__ batch,
                            float* __restrict__ pooled, float* __restrict__ cnt, int n) {
    int tt = blockIdx.x * BLK + threadIdx.x;
    int node = tt >> 2;
    int j = tt & 3;
    int lane = threadIdx.x & 63;
    bool valid = node < n;
    float h[8];
#pragma unroll
    for (int k = 0; k < 8; k++) h[k] = 0.0f;
    int g = -1;
    float c = 0.0f;
    if (valid) {
        int s = rs[node], e = re[node];
        float d = dinv[node];                   // hoisted
        uint4 qs = make_uint4(0, 0, 0, 0);
        int gq = 0;
        if (j == 0) {                           // hoisted self + batch loads
            qs = u2q[node];
            gq = batch[node];
        }
        float acc[8];
#pragma unroll
        for (int k = 0; k < 8; k++) acc[k] = 0.0f;
        int i = s + j;
        for (; i + 12 < e; i += 16) {           // 4 gathers in flight
            uint4 q0 = u2q[sorted[i]];
            uint4 q1 = u2q[sorted[i + 4]];
            uint4 q2 = u2q[sorted[i + 8]];
            uint4 q3 = u2q[sorted[i + 12]];
            h16_add(q0, acc);
            h16_add(q1, acc);
            h16_add(q2, acc);
            h16_add(q3, acc);
        }
        for (; i + 4 < e; i += 8) {             // 2 in flight
            uint4 q0 = u2q[sorted[i]];
            uint4 q1 = u2q[sorted[i + 4]];
            h16_add(q0, acc);
            h16_add(q1, acc);
        }
        if (i < e) {
            uint4 q = u2q[sorted[i]];
            h16_add(q, acc);
        }
        if (j == 0) h16_add(qs, acc);           // self-loop, added once
#pragma unroll
        for (int k = 0; k < 8; k++) {
            acc[k] += __shfl_xor(acc[k], 1, 64);
            acc[k] += __shfl_xor(acc[k], 2, 64);
        }
        if (j == 0) {
#pragma unroll
            for (int k = 0; k < 8; k++) h[k] = tanhf(d * acc[k] + b2[k]);
            g = gq;
            c = 1.0f;
        }
    }
    // stride-4 segmented reduction: base lanes (j==0) hold 16 consecutive
    // nodes per wave; offsets 4..32 only ever read base lanes.
#pragma unroll
    for (int off = 4; off < 64; off <<= 1) {
        int gn = __shfl_down(g, off, 64);
        float cn = __shfl_down(c, off, 64);
        float hn[8];
#pragma unroll
        for (int k = 0; k < 8; k++) hn[k] = __shfl_down(h[k], off, 64);
        bool take = (lane + off < 64) && (gn == g);
        if (take) {
            c += cn;
#pragma unroll
            for (int k = 0; k < 8; k++) h[k] += hn[k];
        }
    }
    int gprev = __shfl_up(g, 4, 64);
    bool head = valid && (j == 0) && (lane == 0 || gprev != g);
    if (head) {
#pragma unroll
        for (int k = 0; k < 8; k++) atomicAdd(&pooled[g * 8 + k], h[k]);
        atomicAdd(&cnt[g], c);
    }
}

// Tiny head: out[g] = dot(pooled[g], W3) / max(cnt,1) + b3
__global__ void k_out(const float* __restrict__ pooled, const float* __restrict__ cnt,
                      const float* __restrict__ W3, const float* __restrict__ b3,
                      float* __restrict__ out, int G) {
    int g = blockIdx.x * BLK + threadIdx.x;
    if (g >= G) return;
    float c = fmaxf(cnt[g], 1.0f);
    float t = 0.0f;
#pragma unroll
    for (int k = 0; k < 8; k++) t += pooled[g * 8 + k] * W3[k];
    out[g] = t / c + b3[0];
}

extern "C" void kernel_launch(void* const* d_in, const int* in_sizes, int n_in,
                              void* d_out, int out_size, void* d_ws, size_t ws_size,
                              hipStream_t stream) {
    const float* x    = (const float*)d_in[0];
    const int*   ei   = (const int*)d_in[1];
    const int*   batch= (const int*)d_in[2];
    const float* Wemb = (const float*)d_in[3];
    const float* bemb = (const float*)d_in[4];
    const float* W1   = (const float*)d_in[5];
    const float* b1   = (const float*)d_in[6];
    const float* W2   = (const float*)d_in[7];
    const float* b2   = (const float*)d_in[8];
    const float* W3   = (const float*)d_in[9];
    const float* b3   = (const float*)d_in[10];
    float* out = (float*)d_out;

    const int n = in_sizes[2];        // 100000
    const int E = in_sizes[1] / 2;    // 3200000
    const int G = out_size;           // 1024
    const int* row = ei;
    const int* col = ei + E;
    const int NB = (n + NPB - 1) / NPB;   // 391

    // workspace (4B words): dinv[n] | u1q(8n reserved, 4n used: fp8 16B/node) |
    //   u2h(4n) | rs[n] | re[n] | bucketCnt[NBMX] | pooled[8G] | cnt[G] |
    //   data[NB*CAPB]  (~20.5 MB)
    float* ws    = (float*)d_ws;
    float* dinv  = ws;                       // n
    uint4* u1q   = (uint4*)(ws + n);         // 4n words used (16 fp8/node)
    __half* u2h  = (__half*)(ws + 9 * n);    // 4n words (8 halves/node)
    int* rs      = (int*)(ws + 13 * n);      // n
    int* re      = rs + n;                   // n
    int* bucketCnt = re + n;                 // NBMX
    float* pooled  = (float*)(bucketCnt + NBMX);   // 8G
    float* cnt     = pooled + 8 * G;               // G
    unsigned int* data = (unsigned int*)(cnt + G); // NB*CAPB

    int gridP = (E + CAPS - 1) / CAPS;       // 521 blocks, chunk = 6144
    int gridA = (4 * n + BLK - 1) / BLK;     // 1563 blocks, 4 lanes/node

    // one memset zeroes bucketCnt + pooled + cnt (contiguous)
    hipMemsetAsync(bucketCnt, 0, (NBMX + 8 * G + G) * sizeof(int), stream);
    k_place<<<gridP, PBLK, 0, stream>>>((const int4*)row, (const int4*)col,
                                        bucketCnt, data, E, NB);
    k_sort_node1<<<NB, SBLK, 0, stream>>>(data, bucketCnt, (const float4*)x,
                                          Wemb, bemb, W1, rs, re, dinv, u1q, n);
    k_agg1<<<gridA, BLK, 0, stream>>>(data, rs, re, u1q,
                                      dinv, b1, W2, (uint4*)u2h, n);
    k_agg2_pool<<<gridA, BLK, 0, stream>>>(data, rs, re,
                                           (const uint4*)u2h, dinv, b2,
                                           batch, pooled, cnt, n);
    k_out<<<(G + BLK - 1) / BLK, BLK, 0, stream>>>(pooled, cnt, W3, b3, out, G);
}